// Round 6
// baseline (560.225 us; speedup 1.0000x reference)
//
#include <hip/hip_runtime.h>
#include <math.h>

// HAN (2-layer) on MI355X.
// GEMMs: LDS-free split-bf16 MFMA — both operands pre-split into bf16 hi/lo
// "images" in global memory; fragments loaded per-lane (16B) straight from
// L1/L2. Aggregation writes hi/lo images directly, so no in-GEMM conversion.
// Layer-2 computes only author-needed work.

#define NA 20000
#define NP 30000
#define NE 200000
#define D1 256   // HID
#define D2 128   // OUT

typedef __attribute__((ext_vector_type(8))) short short8v;
typedef __attribute__((ext_vector_type(4))) float floatx4;
typedef __attribute__((ext_vector_type(8))) unsigned short ushort8v;
typedef __attribute__((ext_vector_type(4))) unsigned short ushort4v;

static __device__ __forceinline__ float lrelu(float x) { return x >= 0.f ? x : 0.2f * x; }

static __device__ __forceinline__ unsigned short bftrunc(float x) {
    return (unsigned short)(__float_as_uint(x) >> 16);
}
static __device__ __forceinline__ float bf2f(unsigned short b) {
    return __uint_as_float(((unsigned)b) << 16);
}
// round-to-nearest-even f32 -> bf16
static __device__ __forceinline__ unsigned short bfrn(float x) {
    unsigned u = __float_as_uint(x);
    return (unsigned short)((u + 0x7FFFu + ((u >> 16) & 1u)) >> 16);
}

static inline int cdiv(int a, int b) { return (a + b - 1) / b; }

// ================= CSR build (4 edge types batched) =================
struct CsrBatch {
    const int* srcv[4];
    const int* dstv[4];
    int* cnt[4];
    int* csrc[4];
    int* cdst[4];
};

__global__ __launch_bounds__(256) void count_deg_b(CsrBatch c, int n) {
    const int ty = blockIdx.y;
    const int i = blockIdx.x * 256 + threadIdx.x;
    if (i < n) atomicAdd(&c.cnt[ty][c.dstv[ty][i]], 1);
}

__global__ __launch_bounds__(256) void fill_csr_b(CsrBatch c, int n) {
    const int ty = blockIdx.y;
    const int i = blockIdx.x * 256 + threadIdx.x;
    if (i < n) {
        const int d = c.dstv[ty][i];
        const int p = atomicAdd(&c.cnt[ty][d], 1);
        c.csrc[ty][p] = c.srcv[ty][i];
        c.cdst[ty][p] = d;
    }
}

// 4 edge-type exclusive scans in one launch (blockIdx = type), wave-shuffle based.
__global__ __launch_bounds__(1024) void exscan4(int* __restrict__ curbase,
                                                int* __restrict__ rpbase) {
    const int off_c[4] = {0, NP, NP + NA, NP + NA + NP};
    const int off_r[4] = {0, NP + 1, NP + NA + 2, NP + NA + NP + 3};
    const int ns[4] = {NP, NA, NP, NA};
    const int b = blockIdx.x;
    int* cur = curbase + off_c[b];
    int* rp = rpbase + off_r[b];
    const int n = ns[b];
    __shared__ int wsum[16];
    __shared__ int carry_s;
    const int t = threadIdx.x, wv = t >> 6, ln = t & 63;
    if (t == 0) carry_s = 0;
    __syncthreads();
    for (int base = 0; base < n; base += 1024) {
        const int i = base + t;
        const int v = (i < n) ? cur[i] : 0;
        int x = v;
#pragma unroll
        for (int off = 1; off < 64; off <<= 1) {
            int y = __shfl_up(x, off);
            if (ln >= off) x += y;
        }
        if (ln == 63) wsum[wv] = x;
        __syncthreads();
        if (wv == 0) {
            int s = (ln < 16) ? wsum[ln] : 0;
#pragma unroll
            for (int off = 1; off < 16; off <<= 1) {
                int y = __shfl_up(s, off);
                if (ln >= off) s += y;
            }
            if (ln < 16) wsum[ln] = s;
        }
        __syncthreads();
        const int woff = (wv == 0) ? 0 : wsum[wv - 1];
        const int c = carry_s;
        const int ex = c + woff + x - v;
        if (i < n) { rp[i] = ex; cur[i] = ex; }
        __syncthreads();
        if (t == 1023) carry_s = c + wsum[15];
        __syncthreads();
    }
    if (t == 0) rp[n] = carry_s;
}

// ============ W -> split-bf16 fragment-major images: [kt][part][col][32] ============
struct PrepBatch {
    const float* W[6];
    unsigned short* img[6];
    int N[6];
    int nsl[6];   // (K/32)*2*N*4 slots of 8 ushorts
};

__global__ __launch_bounds__(256) void w_prep(PrepBatch p) {
    const int m = blockIdx.y;
    const int idx = blockIdx.x * 256 + threadIdx.x;
    if (idx >= p.nsl[m]) return;
    const int N = p.N[m];
    const int slot = idx & 3;
    const int col = (idx >> 2) % N;
    const int rest = (idx >> 2) / N;
    const int part = rest & 1;
    const int kt = rest >> 1;
    unsigned short* dst = p.img[m] + (((size_t)(kt * 2 + part) * N + col) * 32) + slot * 8;
    const float* wsrc = p.W[m] + (size_t)(kt * 32 + slot * 8) * N + col;
    short8v o;
#pragma unroll
    for (int k = 0; k < 8; ++k) {
        const float x = wsrc[(size_t)k * N];
        const unsigned short hb = bftrunc(x);
        o[k] = part ? (short)bftrunc(x - bf2f(hb)) : (short)hb;
    }
    *(short8v*)dst = o;
}

// ============ x (f32) -> split hi/lo bf16 images ============
struct XsBatch {
    const float* x[2];
    unsigned short* hi[2];
    unsigned short* lo[2];
    int n8[2];
};

__global__ __launch_bounds__(256) void xsplit(XsBatch p) {
    const int m = blockIdx.y;
    const int i = blockIdx.x * 256 + threadIdx.x;
    if (i >= p.n8[m]) return;
    const float* xp = p.x[m] + (size_t)i * 8;
    float4 v0 = *(const float4*)xp;
    float4 v1 = *(const float4*)(xp + 4);
    const float xs8[8] = {v0.x, v0.y, v0.z, v0.w, v1.x, v1.y, v1.z, v1.w};
    short8v hi, lo;
#pragma unroll
    for (int k = 0; k < 8; ++k) {
        const unsigned short hb = bftrunc(xs8[k]);
        hi[k] = (short)hb;
        lo[k] = (short)bftrunc(xs8[k] - bf2f(hb));
    }
    *(short8v*)&p.hi[m][(size_t)i * 8] = hi;
    *(short8v*)&p.lo[m][(size_t)i * 8] = lo;
}

// ================= LDS-free split-bf16 MFMA GEMM, batched over blockIdx.y =================
// A: hi/lo bf16 images [M][K]; W: fragment-major image. No LDS, no barriers.
// SCORE=false: C[ty] = bf16_rn(A@W + bias);  SCORE=true: atomicAdd(score[ty], sum tanh(.)*qv)
template <int NT>
struct GemmBatch {
    const unsigned short* Ahi[NT];
    const unsigned short* Alo[NT];
    const unsigned short* Wimg[NT];
    const float* bias[NT];
    unsigned short* C[NT];
    int M[NT];
};

template <int BN, bool SCORE, int NT>
__global__ __launch_bounds__(256) void gemm_img(
    GemmBatch<NT> g, const float* __restrict__ qv, float* __restrict__ score, int K) {
    constexpr int WGN = BN / 64;      // waves along N: 4 (BN=256) or 2 (BN=128)
    constexpr int WGM = 4 / WGN;      // waves along M: 1 or 2
    constexpr int BM = WGM * 64;
    const int ty = blockIdx.y;
    const int M = g.M[ty];
    const int bm = blockIdx.x * BM;
    if (bm >= M) return;
    const unsigned short* __restrict__ Ah = g.Ahi[ty];
    const unsigned short* __restrict__ Al = g.Alo[ty];
    const unsigned short* __restrict__ Wi = g.Wimg[ty];
    const float* __restrict__ bias = g.bias[ty];
    const int t = threadIdx.x;
    const int lane = t & 63, wid = t >> 6;
    const int wr = wid / WGN, wc = wid % WGN;
    const int fq = lane >> 4, fr = lane & 15;
    // per-lane row/col indices (clamped row: OOB rows compute garbage, never stored)
    int arow[4];
    size_t boff[4];
#pragma unroll
    for (int f = 0; f < 4; ++f) {
        const int gr = bm + wr * 64 + f * 16 + fr;
        arow[f] = (gr < M) ? gr : (M - 1);
        const int col = wc * 64 + f * 16 + fr;
        boff[f] = (size_t)col * 32 + fq * 8;
    }
    floatx4 acc[4][4];
#pragma unroll
    for (int i = 0; i < 4; ++i)
#pragma unroll
        for (int j = 0; j < 4; ++j) acc[i][j] = {0.f, 0.f, 0.f, 0.f};

    for (int kt = 0; kt < K; kt += 32) {
        short8v ah[4], al[4], bh[4], bl[4];
        const size_t wbase = (size_t)(kt >> 5) * (2 * BN * 32);
#pragma unroll
        for (int f = 0; f < 4; ++f) {
            const size_t aoff = (size_t)arow[f] * K + kt + fq * 8;
            ah[f] = *(const short8v*)&Ah[aoff];
            al[f] = *(const short8v*)&Al[aoff];
            bh[f] = *(const short8v*)&Wi[wbase + boff[f]];
            bl[f] = *(const short8v*)&Wi[wbase + (size_t)BN * 32 + boff[f]];
        }
#pragma unroll
        for (int i = 0; i < 4; ++i)
#pragma unroll
            for (int j = 0; j < 4; ++j) {
                acc[i][j] = __builtin_amdgcn_mfma_f32_16x16x32_bf16(ah[i], bh[j], acc[i][j], 0, 0, 0);
                acc[i][j] = __builtin_amdgcn_mfma_f32_16x16x32_bf16(ah[i], bl[j], acc[i][j], 0, 0, 0);
                acc[i][j] = __builtin_amdgcn_mfma_f32_16x16x32_bf16(al[i], bh[j], acc[i][j], 0, 0, 0);
            }
    }
    if constexpr (!SCORE) {
        unsigned short* __restrict__ Cb = g.C[ty];
#pragma unroll
        for (int i = 0; i < 4; ++i) {
            const int gr0 = bm + wr * 64 + i * 16 + fq * 4;
#pragma unroll
            for (int j = 0; j < 4; ++j) {
                const int col = wc * 64 + j * 16 + fr;
                const float b = bias[col];
#pragma unroll
                for (int r = 0; r < 4; ++r) {
                    const int gr = gr0 + r;
                    if (gr < M) Cb[(size_t)gr * BN + col] = bfrn(acc[i][j][r] + b);
                }
            }
        }
    } else {
        __shared__ float red[256];
        float partial = 0.f;
#pragma unroll
        for (int i = 0; i < 4; ++i) {
            const int gr0 = bm + wr * 64 + i * 16 + fq * 4;
#pragma unroll
            for (int j = 0; j < 4; ++j) {
                const int col = wc * 64 + j * 16 + fr;
                const float b = bias[col], q = qv[col];
#pragma unroll
                for (int r = 0; r < 4; ++r) {
                    if (gr0 + r < M) partial += tanhf(acc[i][j][r] + b) * q;
                }
            }
        }
        red[t] = partial;
        __syncthreads();
        for (int s = 128; s > 0; s >>= 1) {
            if (t < s) red[t] += red[t + s];
            __syncthreads();
        }
        if (t == 0) atomicAdd(&score[ty], red[0]);
    }
}

// ================ fused node attention-score dots (bf16 h, up to 4 att vectors) ================
template <int HD, int NSC>
__global__ __launch_bounds__(256) void node_scoresN(
    const unsigned short* __restrict__ hx,
    const float* __restrict__ a0, const float* __restrict__ a1,
    const float* __restrict__ a2, const float* __restrict__ a3,
    float* __restrict__ o0, float* __restrict__ o1,
    float* __restrict__ o2, float* __restrict__ o3, int n) {
    const int idx = blockIdx.x * blockDim.x + threadIdx.x;
    const int node = idx >> 2, hh = idx & 3;
    if (node >= n) return;
    const unsigned short* row = hx + (size_t)node * (4 * HD) + hh * HD;
    float s0 = 0.f, s1 = 0.f, s2 = 0.f, s3 = 0.f;
#pragma unroll
    for (int d = 0; d < HD; d += 4) {
        ushort4v xv = *(const ushort4v*)&row[d];
        const float x0 = bf2f(xv[0]), x1 = bf2f(xv[1]), x2 = bf2f(xv[2]), x3 = bf2f(xv[3]);
        float4 v = *(const float4*)&a0[hh * HD + d];
        s0 += x0 * v.x + x1 * v.y + x2 * v.z + x3 * v.w;
        if constexpr (NSC > 1) {
            v = *(const float4*)&a1[hh * HD + d];
            s1 += x0 * v.x + x1 * v.y + x2 * v.z + x3 * v.w;
        }
        if constexpr (NSC > 2) {
            v = *(const float4*)&a2[hh * HD + d];
            s2 += x0 * v.x + x1 * v.y + x2 * v.z + x3 * v.w;
        }
        if constexpr (NSC > 3) {
            v = *(const float4*)&a3[hh * HD + d];
            s3 += x0 * v.x + x1 * v.y + x2 * v.z + x3 * v.w;
        }
    }
    o0[idx] = s0;
    if constexpr (NSC > 1) o1[idx] = s1;
    if constexpr (NSC > 2) o2[idx] = s2;
    if constexpr (NSC > 3) o3[idx] = s3;
}

// ================= per-edge 4-head logits (batched) =================
template <int NT>
struct ElogBatch {
    const int* csrc[NT];
    const int* cdst[NT];
    const float* ss[NT];
    const float* sd[NT];
    float4* alog[NT];
};

template <int NT>
__global__ __launch_bounds__(256) void edge_logits_b(ElogBatch<NT> a, int n) {
    const int ty = blockIdx.y;
    const int i = blockIdx.x * 256 + threadIdx.x;
    if (i >= n) return;
    const int s = a.csrc[ty][i], d = a.cdst[ty][i];
    const float4 av = *(const float4*)&a.ss[ty][s * 4];
    const float4 bv = *(const float4*)&a.sd[ty][d * 4];
    float4 o = {lrelu(av.x + bv.x), lrelu(av.y + bv.y), lrelu(av.z + bv.z), lrelu(av.w + bv.w)};
    a.alog[ty][i] = o;
}

// ========== fused segment softmax + bf16 gather + relu -> split hi/lo images ==========
template <int EPL>
static __device__ __forceinline__ void accum(const unsigned short* p, float ea, float* acc) {
#pragma unroll
    for (int w = 0; w < EPL / 8; ++w) {
        ushort8v x = *(const ushort8v*)(p + w * 8);
#pragma unroll
        for (int k = 0; k < 8; ++k) acc[w * 8 + k] += bf2f(x[k]) * ea;
    }
}

template <int NT>
struct AggBatch {
    const unsigned short* xs[NT];
    const float* alog[NT];
    const int* csrc[NT];
    const int* rowptr[NT];
    unsigned short* outh[NT];
    unsigned short* outl[NT];
    int ndst[NT];
};

// 256 threads = 16 groups of 16 lanes; group -> one dst node; lane owns EPL elems.
template <int D, int NT>
__global__ __launch_bounds__(256) void agg_b(AggBatch<NT> a) {
    constexpr int EPL = D / 16;
    const int ty = blockIdx.y;
    const int gid = blockIdx.x * 16 + (threadIdx.x >> 4);
    if (gid >= a.ndst[ty]) return;
    const int g = threadIdx.x & 15;
    const int h = g >> 2, sub = g & 3;
    const int* __restrict__ rp = a.rowptr[ty];
    const int e0 = rp[gid], e1 = rp[gid + 1];
    const float* __restrict__ lg = a.alog[ty];
    const int* __restrict__ cs = a.csrc[ty];
    const unsigned short* __restrict__ xs = a.xs[ty];
    float mx = -INFINITY;
    for (int e = e0 + sub; e < e1; e += 4)
        mx = fmaxf(mx, lg[(size_t)e * 4 + h]);
    mx = fmaxf(mx, __shfl_xor(mx, 1));
    mx = fmaxf(mx, __shfl_xor(mx, 2));
    float acc[EPL] = {};
    float denom = 0.f;
    int e = e0;
    for (; e + 2 <= e1; e += 2) {
        const int r0 = cs[e], r1 = cs[e + 1];
        const float l0 = lg[(size_t)e * 4 + h];
        const float l1 = lg[(size_t)(e + 1) * 4 + h];
        const float ea0 = __expf(l0 - mx), ea1 = __expf(l1 - mx);
        denom += ea0 + ea1;
        accum<EPL>(xs + (size_t)r0 * D + g * EPL, ea0, acc);
        accum<EPL>(xs + (size_t)r1 * D + g * EPL, ea1, acc);
    }
    if (e < e1) {
        const int r0 = cs[e];
        const float l0 = lg[(size_t)e * 4 + h];
        const float ea0 = __expf(l0 - mx);
        denom += ea0;
        accum<EPL>(xs + (size_t)r0 * D + g * EPL, ea0, acc);
    }
    const float inv = 1.f / (denom + 1e-16f);
    unsigned short* __restrict__ oh = a.outh[ty] + (size_t)gid * D + g * EPL;
    unsigned short* __restrict__ ol = a.outl[ty] + (size_t)gid * D + g * EPL;
#pragma unroll
    for (int w = 0; w < EPL / 8; ++w) {
        short8v hv, lv;
#pragma unroll
        for (int k = 0; k < 8; ++k) {
            const float v = fmaxf(acc[w * 8 + k] * inv, 0.f);
            const unsigned short hb = bftrunc(v);
            hv[k] = (short)hb;
            lv[k] = (short)bftrunc(v - bf2f(hb));
        }
        *(short8v*)&oh[w * 8] = hv;
        *(short8v*)&ol[w * 8] = lv;
    }
}

// ================= semantic softmax + combine (image pairs -> image pair) =================
struct CombImgBatch {
    const unsigned short* ah[2];
    const unsigned short* al[2];
    const unsigned short* bh[2];
    const unsigned short* bl[2];
    unsigned short* oh[2];
    unsigned short* ol[2];
    int n8[2];
    int slot[2];
    float invN[2];
};

__global__ __launch_bounds__(256) void combine_img(CombImgBatch c, const float* __restrict__ sc) {
    const int ty = blockIdx.y;
    const int i = blockIdx.x * 256 + threadIdx.x;
    if (i >= c.n8[ty]) return;
    const float s0 = sc[c.slot[ty]] * c.invN[ty];
    const float s1 = sc[c.slot[ty] + 1] * c.invN[ty];
    const float m = fmaxf(s0, s1);
    const float e0 = expf(s0 - m), e1 = expf(s1 - m);
    const float w0 = e0 / (e0 + e1), w1 = e1 / (e0 + e1);
    const size_t o = (size_t)i * 8;
    ushort8v xh = *(const ushort8v*)&c.ah[ty][o];
    ushort8v xl = *(const ushort8v*)&c.al[ty][o];
    ushort8v yh = *(const ushort8v*)&c.bh[ty][o];
    ushort8v yl = *(const ushort8v*)&c.bl[ty][o];
    short8v hv, lv;
#pragma unroll
    for (int k = 0; k < 8; ++k) {
        const float x = bf2f(xh[k]) + bf2f(xl[k]);
        const float y = bf2f(yh[k]) + bf2f(yl[k]);
        const float v = w0 * x + w1 * y;
        const unsigned short hb = bftrunc(v);
        hv[k] = (short)hb;
        lv[k] = (short)bftrunc(v - bf2f(hb));
    }
    *(short8v*)&c.oh[ty][o] = hv;
    *(short8v*)&c.ol[ty][o] = lv;
}

// final combine: image pairs -> f32 output
__global__ __launch_bounds__(256) void combine_out(
    const unsigned short* __restrict__ ah, const unsigned short* __restrict__ al,
    const unsigned short* __restrict__ bh, const unsigned short* __restrict__ bl,
    float* __restrict__ out, const float* __restrict__ sc, int slot, float invN, int n8) {
    const int i = blockIdx.x * 256 + threadIdx.x;
    if (i >= n8) return;
    const float s0 = sc[slot] * invN, s1 = sc[slot + 1] * invN;
    const float m = fmaxf(s0, s1);
    const float e0 = expf(s0 - m), e1 = expf(s1 - m);
    const float w0 = e0 / (e0 + e1), w1 = e1 / (e0 + e1);
    const size_t o = (size_t)i * 8;
    ushort8v xh = *(const ushort8v*)&ah[o];
    ushort8v xl = *(const ushort8v*)&al[o];
    ushort8v yh = *(const ushort8v*)&bh[o];
    ushort8v yl = *(const ushort8v*)&bl[o];
    float4 r0, r1;
    float rr[8];
#pragma unroll
    for (int k = 0; k < 8; ++k) {
        const float x = bf2f(xh[k]) + bf2f(xl[k]);
        const float y = bf2f(yh[k]) + bf2f(yl[k]);
        rr[k] = w0 * x + w1 * y;
    }
    r0 = {rr[0], rr[1], rr[2], rr[3]};
    r1 = {rr[4], rr[5], rr[6], rr[7]};
    *(float4*)&out[o] = r0;
    *(float4*)&out[o + 4] = r1;
}

extern "C" void kernel_launch(void* const* d_in, const int* in_sizes, int n_in,
                              void* d_out, int out_size, void* d_ws, size_t ws_size,
                              hipStream_t stream) {
    const float* x_a = (const float*)d_in[0];
    const float* x_p = (const float*)d_in[1];
    const int* src[4] = {(const int*)d_in[2], (const int*)d_in[4], (const int*)d_in[6], (const int*)d_in[8]};
    const int* dst[4] = {(const int*)d_in[3], (const int*)d_in[5], (const int*)d_in[7], (const int*)d_in[9]};
    const float* W1a = (const float*)d_in[10]; const float* b1a = (const float*)d_in[11];
    const float* W1p = (const float*)d_in[12]; const float* b1p = (const float*)d_in[13];
    const float* att1s = (const float*)d_in[14]; const float* att1d = (const float*)d_in[15];
    const float* q1 = (const float*)d_in[16];
    const float* k1W = (const float*)d_in[17]; const float* k1b = (const float*)d_in[18];
    const float* W2a = (const float*)d_in[19]; const float* b2a = (const float*)d_in[20];
    const float* W2p = (const float*)d_in[21]; const float* b2p = (const float*)d_in[22];
    const float* att2s = (const float*)d_in[23]; const float* att2d = (const float*)d_in[24];
    const float* q2 = (const float*)d_in[25];
    const float* k2W = (const float*)d_in[26]; const float* k2b = (const float*)d_in[27];

    // ---- workspace layout ----
    char* wp = (char*)d_ws;
    unsigned short* h1a_bf = (unsigned short*)wp; wp += (size_t)NA * D1 * 2;
    unsigned short* h1p_bf = (unsigned short*)wp; wp += (size_t)NP * D1 * 2;
    // agg slots (each holds an hi/lo bf16 image pair; same bytes as old f32)
    char* agg0c = wp; wp += (size_t)NP * D1 * 4;
    char* agg1c = wp; wp += (size_t)NA * D1 * 4;
    char* agg2c = wp; wp += (size_t)NP * D1 * 4;
    char* agg3c = wp; wp += (size_t)NA * D1 * 4;
    float* sv = (float*)wp; wp += (size_t)(16 * NA + 16 * NP) * 4;
    float4* alogb = (float4*)wp; wp += (size_t)4 * NE * 16;
    float* sc = (float*)wp; wp += 16 * 4;
    int* rp_base = (int*)wp; wp += (size_t)(NP + NA + NP + NA + 4) * 4;
    int* cur_base = (int*)wp; wp += (size_t)(NP + NA + NP + NA) * 4;
    int* csrc_base = (int*)wp; wp += (size_t)4 * NE * 4;
    int* cdst_base = (int*)wp; wp += (size_t)4 * NE * 4;
    // W images: [K/32][2][N][32] ushort
    unsigned short* img_w1a = (unsigned short*)wp; wp += (size_t)8 * 2 * 256 * 32 * 2;
    unsigned short* img_w1p = (unsigned short*)wp; wp += (size_t)8 * 2 * 256 * 32 * 2;
    unsigned short* img_k1w = (unsigned short*)wp; wp += (size_t)8 * 2 * 256 * 32 * 2;
    unsigned short* img_w2a = (unsigned short*)wp; wp += (size_t)8 * 2 * 128 * 32 * 2;
    unsigned short* img_w2p = (unsigned short*)wp; wp += (size_t)8 * 2 * 128 * 32 * 2;
    unsigned short* img_k2w = (unsigned short*)wp; wp += (size_t)4 * 2 * 128 * 32 * 2;
    const size_t need_bytes = (size_t)(wp - (char*)d_ws);
    if (ws_size < need_bytes) return;

    int* rp[4] = {rp_base, rp_base + NP + 1, rp_base + NP + NA + 2, rp_base + NP + NA + NP + 3};
    int* cur[4] = {cur_base, cur_base + NP, cur_base + NP + NA, cur_base + NP + NA + NP};
    int* csrc[4]; int* cdst[4]; float4* alog[4];
    for (int i = 0; i < 4; ++i) {
        csrc[i] = csrc_base + (size_t)i * NE;
        cdst[i] = cdst_base + (size_t)i * NE;
        alog[i] = alogb + (size_t)i * NE;
    }
    float* ss0 = sv;             float* sd0 = ss0 + NA * 4;
    float* ss1 = sd0 + NP * 4;   float* sd1 = ss1 + NP * 4;
    float* ss2 = sd1 + NA * 4;   float* sd2 = ss2 + NP * 4;
    float* ss3 = sd2 + NP * 4;   float* sd3 = ss3 + NA * 4;

    // x images alias agg0..agg1 (x dead before agg written; stream-ordered)
    unsigned short* xa_hi = (unsigned short*)agg0c;
    unsigned short* xa_lo = xa_hi + (size_t)NA * D1;
    unsigned short* xp_hi = xa_lo + (size_t)NA * D1;
    unsigned short* xp_lo = xp_hi + (size_t)NP * D1;
    // agg image pairs in their slots
    unsigned short* a0h = (unsigned short*)agg0c; unsigned short* a0l = a0h + (size_t)NP * D1;
    unsigned short* a1h = (unsigned short*)agg1c; unsigned short* a1l = a1h + (size_t)NA * D1;
    unsigned short* a2h = (unsigned short*)agg2c; unsigned short* a2l = a2h + (size_t)NP * D1;
    unsigned short* a3h = (unsigned short*)agg3c; unsigned short* a3l = a3h + (size_t)NA * D1;
    // res image pairs (in-place over agg0/agg1 slots)
    unsigned short* rph = a0h; unsigned short* rpl = a0l;   // res_p [NP,256]
    unsigned short* rah = a1h; unsigned short* ral = a1l;   // res_a [NA,256]
    // layer-2 feature bf16 (agg2 slot) and g image pairs (agg3 slot)
    unsigned short* h2a_bf = (unsigned short*)agg2c;
    unsigned short* h2p_bf = h2a_bf + (size_t)NA * D2;
    unsigned short* g21h = (unsigned short*)agg3c; unsigned short* g21l = g21h + (size_t)NA * D2;
    unsigned short* g23h = g21l + (size_t)NA * D2; unsigned short* g23l = g23h + (size_t)NA * D2;
    float* ss21 = sv;             float* sd21 = ss21 + NP * 4;
    float* ss23 = sd21 + NA * 4;  float* sd23 = ss23 + NA * 4;

    // ---- 0. zero counters, W prep, x split ----
    hipMemsetAsync(cur_base, 0, (size_t)(NP + NA + NP + NA) * sizeof(int), stream);
    hipMemsetAsync(sc, 0, 16 * sizeof(float), stream);
    PrepBatch pb = {{W1a, W1p, k1W, W2a, W2p, k2W},
                    {img_w1a, img_w1p, img_k1w, img_w2a, img_w2p, img_k2w},
                    {256, 256, 256, 128, 128, 128},
                    {8 * 2 * 256 * 4, 8 * 2 * 256 * 4, 8 * 2 * 256 * 4,
                     8 * 2 * 128 * 4, 8 * 2 * 128 * 4, 4 * 2 * 128 * 4}};
    w_prep<<<dim3(cdiv(8 * 2 * 256 * 4, 256), 6), 256, 0, stream>>>(pb);
    XsBatch xb = {{x_a, x_p}, {xa_hi, xp_hi}, {xa_lo, xp_lo},
                  {NA * D1 / 8, NP * D1 / 8}};
    xsplit<<<dim3(cdiv(NP * D1 / 8, 256), 2), 256, 0, stream>>>(xb);

    // ---- 1. CSR build ----
    CsrBatch cb;
    for (int i = 0; i < 4; ++i) {
        cb.srcv[i] = src[i]; cb.dstv[i] = dst[i];
        cb.cnt[i] = cur[i]; cb.csrc[i] = csrc[i]; cb.cdst[i] = cdst[i];
    }
    count_deg_b<<<dim3(cdiv(NE, 256), 4), 256, 0, stream>>>(cb, NE);
    exscan4<<<4, 1024, 0, stream>>>(cur_base, rp_base);
    fill_csr_b<<<dim3(cdiv(NE, 256), 4), 256, 0, stream>>>(cb, NE);

    // ---- 2. layer-1 transforms -> bf16 h (batched, LDS-free) ----
    GemmBatch<2> t1 = {{xa_hi, xp_hi}, {xa_lo, xp_lo}, {img_w1a, img_w1p},
                       {b1a, b1p}, {h1a_bf, h1p_bf}, {NA, NP}};
    gemm_img<256, false, 2><<<dim3(cdiv(NP, 64), 2), 256, 0, stream>>>(t1, nullptr, nullptr, 256);

    // ---- 3. fused node attention scalars (layer 1) ----
    node_scoresN<64, 4><<<cdiv(NA * 4, 256), 256, 0, stream>>>(
        h1a_bf, att1s + 0 * 256, att1d + 1 * 256, att1s + 3 * 256, att1d + 3 * 256,
        ss0, sd1, ss3, sd3, NA);
    node_scoresN<64, 4><<<cdiv(NP * 4, 256), 256, 0, stream>>>(
        h1p_bf, att1d + 0 * 256, att1s + 1 * 256, att1s + 2 * 256, att1d + 2 * 256,
        sd0, ss1, ss2, sd2, NP);

    // ---- 4. per-edge logits + fused aggregation -> split images ----
    ElogBatch<4> el1 = {{csrc[0], csrc[1], csrc[2], csrc[3]},
                        {cdst[0], cdst[1], cdst[2], cdst[3]},
                        {ss0, ss1, ss2, ss3}, {sd0, sd1, sd2, sd3},
                        {alog[0], alog[1], alog[2], alog[3]}};
    edge_logits_b<4><<<dim3(cdiv(NE, 256), 4), 256, 0, stream>>>(el1, NE);
    AggBatch<4> ab1 = {{h1a_bf, h1p_bf, h1p_bf, h1a_bf},
                       {(const float*)alog[0], (const float*)alog[1], (const float*)alog[2], (const float*)alog[3]},
                       {csrc[0], csrc[1], csrc[2], csrc[3]},
                       {rp[0], rp[1], rp[2], rp[3]},
                       {a0h, a1h, a2h, a3h}, {a0l, a1l, a2l, a3l},
                       {NP, NA, NP, NA}};
    agg_b<256, 4><<<dim3(cdiv(NP, 16), 4), 256, 0, stream>>>(ab1);

    // ---- 5. semantic scores (layer 1, batched) + combine (softmax folded) ----
    GemmBatch<4> s1 = {{a0h, a2h, a1h, a3h}, {a0l, a2l, a1l, a3l},
                       {img_k1w, img_k1w, img_k1w, img_k1w},
                       {k1b, k1b, k1b, k1b},
                       {nullptr, nullptr, nullptr, nullptr},
                       {NP, NP, NA, NA}};
    gemm_img<256, true, 4><<<dim3(cdiv(NP, 64), 4), 256, 0, stream>>>(s1, q1, sc, 256);
    CombImgBatch c1 = {{a0h, a1h}, {a0l, a1l}, {a2h, a3h}, {a2l, a3l},
                       {rph, rah}, {rpl, ral},
                       {NP * D1 / 8, NA * D1 / 8}, {0, 2}, {1.f / NP, 1.f / NA}};
    combine_img<<<dim3(cdiv(NP * D1 / 8, 256), 2), 256, 0, stream>>>(c1, sc);

    // ---- 6. layer-2 transforms -> bf16 h2 (batched) ----
    GemmBatch<2> t2 = {{rah, rph}, {ral, rpl}, {img_w2a, img_w2p},
                       {b2a, b2p}, {h2a_bf, h2p_bf}, {NA, NP}};
    gemm_img<128, false, 2><<<dim3(cdiv(NP, 128), 2), 256, 0, stream>>>(t2, nullptr, nullptr, 256);

    // ---- 7. layer-2 (author only: edge types 1 p->a, 3 a->a) ----
    node_scoresN<32, 3><<<cdiv(NA * 4, 256), 256, 0, stream>>>(
        h2a_bf, att2d + 1 * 128, att2s + 3 * 128, att2d + 3 * 128, nullptr,
        sd21, ss23, sd23, nullptr, NA);
    node_scoresN<32, 1><<<cdiv(NP * 4, 256), 256, 0, stream>>>(
        h2p_bf, att2s + 1 * 128, nullptr, nullptr, nullptr,
        ss21, nullptr, nullptr, nullptr, NP);
    ElogBatch<2> el2 = {{csrc[1], csrc[3]}, {cdst[1], cdst[3]},
                        {ss21, ss23}, {sd21, sd23}, {alog[1], alog[3]}};
    edge_logits_b<2><<<dim3(cdiv(NE, 256), 2), 256, 0, stream>>>(el2, NE);
    AggBatch<2> ab2 = {{h2p_bf, h2a_bf},
                       {(const float*)alog[1], (const float*)alog[3]},
                       {csrc[1], csrc[3]}, {rp[1], rp[3]},
                       {g21h, g23h}, {g21l, g23l}, {NA, NA}};
    agg_b<128, 2><<<dim3(cdiv(NA, 16), 2), 256, 0, stream>>>(ab2);

    // ---- 8. layer-2 semantic attention -> d_out ----
    GemmBatch<2> s2 = {{g21h, g23h}, {g21l, g23l}, {img_k2w, img_k2w},
                       {k2b, k2b}, {nullptr, nullptr}, {NA, NA}};
    gemm_img<128, true, 2><<<dim3(cdiv(NA, 128), 2), 256, 0, stream>>>(s2, q2, sc + 4, 128);
    combine_out<<<cdiv(NA * D2 / 8, 256), 256, 0, stream>>>(
        g21h, g21l, g23h, g23l, (float*)d_out, sc, 4, 1.f / NA, NA * D2 / 8);
}

// Round 7
// 426.201 us; speedup vs baseline: 1.3145x; 1.3145x over previous
//
#include <hip/hip_runtime.h>
#include <math.h>

// HAN (2-layer) on MI355X.
// GEMMs: A = plain bf16 image, W = split-bf16 hi/lo fragment-major image
// (2 MFMA products). Both staged via global_load_lds (width 16) with k-slot
// XOR swizzle baked into the global source -> conflict-free ds_read_b128.
// Graph aggregation: bf16 gather, 16-lane group per dst node, batched.
// Layer-2 computes only author-needed work.

#define NA 20000
#define NP 30000
#define NE 200000
#define D1 256   // HID
#define D2 128   // OUT

typedef __attribute__((ext_vector_type(8))) short short8v;
typedef __attribute__((ext_vector_type(4))) float floatx4;
typedef __attribute__((ext_vector_type(8))) unsigned short ushort8v;
typedef __attribute__((ext_vector_type(4))) unsigned short ushort4v;

static __device__ __forceinline__ float lrelu(float x) { return x >= 0.f ? x : 0.2f * x; }

static __device__ __forceinline__ unsigned short bftrunc(float x) {
    return (unsigned short)(__float_as_uint(x) >> 16);
}
static __device__ __forceinline__ float bf2f(unsigned short b) {
    return __uint_as_float(((unsigned)b) << 16);
}
// round-to-nearest-even f32 -> bf16
static __device__ __forceinline__ unsigned short bfrn(float x) {
    unsigned u = __float_as_uint(x);
    return (unsigned short)((u + 0x7FFFu + ((u >> 16) & 1u)) >> 16);
}

typedef __attribute__((address_space(1))) const unsigned int as1_uint;
typedef __attribute__((address_space(3))) unsigned int as3_uint;
static __device__ __forceinline__ void gl_lds16(const void* g, void* l) {
    __builtin_amdgcn_global_load_lds((as1_uint*)g, (as3_uint*)l, 16, 0, 0);
}

static inline int cdiv(int a, int b) { return (a + b - 1) / b; }

// ================= CSR build (4 edge types batched) =================
struct CsrBatch {
    const int* srcv[4];
    const int* dstv[4];
    int* cnt[4];
    int* csrc[4];
    int* cdst[4];
};

__global__ __launch_bounds__(256) void count_deg_b(CsrBatch c, int n) {
    const int ty = blockIdx.y;
    const int i = blockIdx.x * 256 + threadIdx.x;
    if (i < n) atomicAdd(&c.cnt[ty][c.dstv[ty][i]], 1);
}

__global__ __launch_bounds__(256) void fill_csr_b(CsrBatch c, int n) {
    const int ty = blockIdx.y;
    const int i = blockIdx.x * 256 + threadIdx.x;
    if (i < n) {
        const int d = c.dstv[ty][i];
        const int p = atomicAdd(&c.cnt[ty][d], 1);
        c.csrc[ty][p] = c.srcv[ty][i];
        c.cdst[ty][p] = d;
    }
}

// 4 edge-type exclusive scans in one launch (blockIdx = type), wave-shuffle based.
__global__ __launch_bounds__(1024) void exscan4(int* __restrict__ curbase,
                                                int* __restrict__ rpbase) {
    const int off_c[4] = {0, NP, NP + NA, NP + NA + NP};
    const int off_r[4] = {0, NP + 1, NP + NA + 2, NP + NA + NP + 3};
    const int ns[4] = {NP, NA, NP, NA};
    const int b = blockIdx.x;
    int* cur = curbase + off_c[b];
    int* rp = rpbase + off_r[b];
    const int n = ns[b];
    __shared__ int wsum[16];
    __shared__ int carry_s;
    const int t = threadIdx.x, wv = t >> 6, ln = t & 63;
    if (t == 0) carry_s = 0;
    __syncthreads();
    for (int base = 0; base < n; base += 1024) {
        const int i = base + t;
        const int v = (i < n) ? cur[i] : 0;
        int x = v;
#pragma unroll
        for (int off = 1; off < 64; off <<= 1) {
            int y = __shfl_up(x, off);
            if (ln >= off) x += y;
        }
        if (ln == 63) wsum[wv] = x;
        __syncthreads();
        if (wv == 0) {
            int s = (ln < 16) ? wsum[ln] : 0;
#pragma unroll
            for (int off = 1; off < 16; off <<= 1) {
                int y = __shfl_up(s, off);
                if (ln >= off) s += y;
            }
            if (ln < 16) wsum[ln] = s;
        }
        __syncthreads();
        const int woff = (wv == 0) ? 0 : wsum[wv - 1];
        const int c = carry_s;
        const int ex = c + woff + x - v;
        if (i < n) { rp[i] = ex; cur[i] = ex; }
        __syncthreads();
        if (t == 1023) carry_s = c + wsum[15];
        __syncthreads();
    }
    if (t == 0) rp[n] = carry_s;
}

// ===== W -> split-bf16 fragment-major swizzled images: [kt][part][col][4 slots][8] =====
// Image position [col][slot] holds W k-elements of slot' = slot ^ ((col>>1)&3).
struct PrepBatch {
    const float* W[6];
    unsigned short* img[6];
    int N[6];
    int nsl[6];
};

__global__ __launch_bounds__(256) void w_prep(PrepBatch p) {
    const int m = blockIdx.y;
    const int idx = blockIdx.x * 256 + threadIdx.x;
    if (idx >= p.nsl[m]) return;
    const int N = p.N[m];
    const int slot = idx & 3;
    const int col = (idx >> 2) % N;
    const int rest = (idx >> 2) / N;
    const int part = rest & 1;
    const int kt = rest >> 1;
    const int ks = slot ^ ((col >> 1) & 3);
    unsigned short* dst = p.img[m] + (((size_t)(kt * 2 + part) * N + col) * 32) + slot * 8;
    const float* wsrc = p.W[m] + (size_t)(kt * 32 + ks * 8) * N + col;
    short8v o;
#pragma unroll
    for (int k = 0; k < 8; ++k) {
        const float x = wsrc[(size_t)k * N];
        const unsigned short hb = bftrunc(x);
        o[k] = part ? (short)bftrunc(x - bf2f(hb)) : (short)hb;
    }
    *(short8v*)dst = o;
}

// ============ x (f32) -> bf16-rn image (batched over 2) ============
struct XrBatch {
    const float* x[2];
    unsigned short* o[2];
    int n8[2];
};

__global__ __launch_bounds__(256) void xround_b(XrBatch p) {
    const int m = blockIdx.y;
    const int i = blockIdx.x * 256 + threadIdx.x;
    if (i >= p.n8[m]) return;
    const float* xp = p.x[m] + (size_t)i * 8;
    float4 v0 = *(const float4*)xp;
    float4 v1 = *(const float4*)(xp + 4);
    const float xs8[8] = {v0.x, v0.y, v0.z, v0.w, v1.x, v1.y, v1.z, v1.w};
    short8v o;
#pragma unroll
    for (int k = 0; k < 8; ++k) o[k] = (short)bfrn(xs8[k]);
    *(short8v*)&p.o[m][(size_t)i * 8] = o;
}

// ============== 2-product MFMA GEMM: A bf16 image, W split image; gl_lds staging ==============
template <int NT>
struct GemmBatch {
    const unsigned short* A[NT];
    const unsigned short* Wimg[NT];
    const float* bias[NT];
    unsigned short* C[NT];
    int M[NT];
};

template <int BN, bool SCORE, int NT>
__global__ __launch_bounds__(256) void gemm_sw(
    GemmBatch<NT> g, const float* __restrict__ qv, float* __restrict__ score, int K) {
    constexpr int WGN = BN / 64;
    constexpr int WGM = 4 / WGN;
    constexpr int BM = WGM * 64;
    constexpr int ACH = BM * 32 * 2 / 1024;
    constexpr int BCH = 2 * BN * 32 * 2 / 1024;
    constexpr int CPW = (ACH + BCH) / 4;
    const int ty = blockIdx.y;
    const int M = g.M[ty];
    const int bm = blockIdx.x * BM;
    if (bm >= M) return;
    const unsigned short* __restrict__ A = g.A[ty];
    const unsigned short* __restrict__ Wi = g.Wimg[ty];
    const float* __restrict__ bias = g.bias[ty];
    __shared__ __attribute__((aligned(16))) unsigned short As[BM][32];
    __shared__ __attribute__((aligned(16))) unsigned short Bs[2][BN][32];
    const int t = threadIdx.x;
    const int lane = t & 63, wid = t >> 6;
    const int wr = wid / WGN, wc = wid % WGN;
    const int fq = lane >> 4, fr = lane & 15;
    const int asl = (fq ^ ((fr >> 1) & 3)) * 16;      // swizzled read slot (A and B)
    const int lr = lane >> 2;                          // staging: row within 1KB chunk
    const int lks = (lane & 3) ^ ((lane >> 3) & 3);    // staging: swizzled source k-slot
    floatx4 acc[4][4];
#pragma unroll
    for (int i = 0; i < 4; ++i)
#pragma unroll
        for (int j = 0; j < 4; ++j) acc[i][j] = {0.f, 0.f, 0.f, 0.f};

    for (int kt = 0; kt < K; kt += 32) {
        const char* wbase = (const char*)Wi + (size_t)(kt >> 5) * (2 * BN * 32 * 2);
#pragma unroll
        for (int ci = 0; ci < CPW; ++ci) {
            const int c = wid * CPW + ci;
            if (c < ACH) {
                const int row = c * 16 + lr;
                const char* srcp = (const char*)(A + (size_t)(bm + row) * K + kt + lks * 8);
                gl_lds16(srcp, (char*)As + c * 1024);
            } else {
                const int bc = c - ACH;
                gl_lds16(wbase + (size_t)bc * 1024 + lane * 16, (char*)Bs + bc * 1024);
            }
        }
        __syncthreads();
        short8v a[4], bh[4], bl[4];
#pragma unroll
        for (int f = 0; f < 4; ++f) {
            const int ar = wr * 64 + f * 16 + fr;
            a[f] = *(const short8v*)((const char*)As + ar * 64 + asl);
            const int bc = wc * 64 + f * 16 + fr;
            bh[f] = *(const short8v*)((const char*)Bs + bc * 64 + asl);
            bl[f] = *(const short8v*)((const char*)Bs + (size_t)BN * 64 + bc * 64 + asl);
        }
#pragma unroll
        for (int i = 0; i < 4; ++i)
#pragma unroll
            for (int j = 0; j < 4; ++j) {
                acc[i][j] = __builtin_amdgcn_mfma_f32_16x16x32_bf16(a[i], bh[j], acc[i][j], 0, 0, 0);
                acc[i][j] = __builtin_amdgcn_mfma_f32_16x16x32_bf16(a[i], bl[j], acc[i][j], 0, 0, 0);
            }
        __syncthreads();
    }
    if constexpr (!SCORE) {
        unsigned short* __restrict__ Cb = g.C[ty];
#pragma unroll
        for (int i = 0; i < 4; ++i) {
            const int gr0 = bm + wr * 64 + i * 16 + fq * 4;
#pragma unroll
            for (int j = 0; j < 4; ++j) {
                const int col = wc * 64 + j * 16 + fr;
                const float b = bias[col];
#pragma unroll
                for (int r = 0; r < 4; ++r) {
                    const int gr = gr0 + r;
                    if (gr < M) Cb[(size_t)gr * BN + col] = bfrn(acc[i][j][r] + b);
                }
            }
        }
    } else {
        __shared__ float red[256];
        float partial = 0.f;
#pragma unroll
        for (int i = 0; i < 4; ++i) {
            const int gr0 = bm + wr * 64 + i * 16 + fq * 4;
#pragma unroll
            for (int j = 0; j < 4; ++j) {
                const int col = wc * 64 + j * 16 + fr;
                const float b = bias[col], q = qv[col];
#pragma unroll
                for (int r = 0; r < 4; ++r) {
                    if (gr0 + r < M) partial += tanhf(acc[i][j][r] + b) * q;
                }
            }
        }
        red[t] = partial;
        __syncthreads();
        for (int s = 128; s > 0; s >>= 1) {
            if (t < s) red[t] += red[t + s];
            __syncthreads();
        }
        if (t == 0) atomicAdd(&score[ty], red[0]);
    }
}

// ================ fused node attention-score dots (bf16 h, up to 4 att vectors) ================
template <int HD, int NSC>
__global__ __launch_bounds__(256) void node_scoresN(
    const unsigned short* __restrict__ hx,
    const float* __restrict__ a0, const float* __restrict__ a1,
    const float* __restrict__ a2, const float* __restrict__ a3,
    float* __restrict__ o0, float* __restrict__ o1,
    float* __restrict__ o2, float* __restrict__ o3, int n) {
    const int idx = blockIdx.x * blockDim.x + threadIdx.x;
    const int node = idx >> 2, hh = idx & 3;
    if (node >= n) return;
    const unsigned short* row = hx + (size_t)node * (4 * HD) + hh * HD;
    float s0 = 0.f, s1 = 0.f, s2 = 0.f, s3 = 0.f;
#pragma unroll
    for (int d = 0; d < HD; d += 4) {
        ushort4v xv = *(const ushort4v*)&row[d];
        const float x0 = bf2f(xv[0]), x1 = bf2f(xv[1]), x2 = bf2f(xv[2]), x3 = bf2f(xv[3]);
        float4 v = *(const float4*)&a0[hh * HD + d];
        s0 += x0 * v.x + x1 * v.y + x2 * v.z + x3 * v.w;
        if constexpr (NSC > 1) {
            v = *(const float4*)&a1[hh * HD + d];
            s1 += x0 * v.x + x1 * v.y + x2 * v.z + x3 * v.w;
        }
        if constexpr (NSC > 2) {
            v = *(const float4*)&a2[hh * HD + d];
            s2 += x0 * v.x + x1 * v.y + x2 * v.z + x3 * v.w;
        }
        if constexpr (NSC > 3) {
            v = *(const float4*)&a3[hh * HD + d];
            s3 += x0 * v.x + x1 * v.y + x2 * v.z + x3 * v.w;
        }
    }
    o0[idx] = s0;
    if constexpr (NSC > 1) o1[idx] = s1;
    if constexpr (NSC > 2) o2[idx] = s2;
    if constexpr (NSC > 3) o3[idx] = s3;
}

// ================= per-edge 4-head logits (batched) =================
template <int NT>
struct ElogBatch {
    const int* csrc[NT];
    const int* cdst[NT];
    const float* ss[NT];
    const float* sd[NT];
    float4* alog[NT];
};

template <int NT>
__global__ __launch_bounds__(256) void edge_logits_b(ElogBatch<NT> a, int n) {
    const int ty = blockIdx.y;
    const int i = blockIdx.x * 256 + threadIdx.x;
    if (i >= n) return;
    const int s = a.csrc[ty][i], d = a.cdst[ty][i];
    const float4 av = *(const float4*)&a.ss[ty][s * 4];
    const float4 bv = *(const float4*)&a.sd[ty][d * 4];
    float4 o = {lrelu(av.x + bv.x), lrelu(av.y + bv.y), lrelu(av.z + bv.z), lrelu(av.w + bv.w)};
    a.alog[ty][i] = o;
}

// ========== fused segment softmax + bf16 gather + relu -> bf16 out ==========
template <int EPL>
static __device__ __forceinline__ void accum(const unsigned short* p, float ea, float* acc) {
#pragma unroll
    for (int w = 0; w < EPL / 8; ++w) {
        ushort8v x = *(const ushort8v*)(p + w * 8);
#pragma unroll
        for (int k = 0; k < 8; ++k) acc[w * 8 + k] += bf2f(x[k]) * ea;
    }
}

template <int NT>
struct AggBatch {
    const unsigned short* xs[NT];
    const float* alog[NT];
    const int* csrc[NT];
    const int* rowptr[NT];
    unsigned short* out[NT];
    int ndst[NT];
};

template <int D, int NT>
__global__ __launch_bounds__(256) void agg_b(AggBatch<NT> a) {
    constexpr int EPL = D / 16;
    const int ty = blockIdx.y;
    const int gid = blockIdx.x * 16 + (threadIdx.x >> 4);
    if (gid >= a.ndst[ty]) return;
    const int g = threadIdx.x & 15;
    const int h = g >> 2, sub = g & 3;
    const int* __restrict__ rp = a.rowptr[ty];
    const int e0 = rp[gid], e1 = rp[gid + 1];
    const float* __restrict__ lg = a.alog[ty];
    const int* __restrict__ cs = a.csrc[ty];
    const unsigned short* __restrict__ xs = a.xs[ty];
    float mx = -INFINITY;
    for (int e = e0 + sub; e < e1; e += 4)
        mx = fmaxf(mx, lg[(size_t)e * 4 + h]);
    mx = fmaxf(mx, __shfl_xor(mx, 1));
    mx = fmaxf(mx, __shfl_xor(mx, 2));
    float acc[EPL] = {};
    float denom = 0.f;
    int e = e0;
    for (; e + 2 <= e1; e += 2) {
        const int r0 = cs[e], r1 = cs[e + 1];
        const float l0 = lg[(size_t)e * 4 + h];
        const float l1 = lg[(size_t)(e + 1) * 4 + h];
        const float ea0 = __expf(l0 - mx), ea1 = __expf(l1 - mx);
        denom += ea0 + ea1;
        accum<EPL>(xs + (size_t)r0 * D + g * EPL, ea0, acc);
        accum<EPL>(xs + (size_t)r1 * D + g * EPL, ea1, acc);
    }
    if (e < e1) {
        const int r0 = cs[e];
        const float l0 = lg[(size_t)e * 4 + h];
        const float ea0 = __expf(l0 - mx);
        denom += ea0;
        accum<EPL>(xs + (size_t)r0 * D + g * EPL, ea0, acc);
    }
    const float inv = 1.f / (denom + 1e-16f);
    unsigned short* __restrict__ orow = a.out[ty] + (size_t)gid * D + g * EPL;
#pragma unroll
    for (int w = 0; w < EPL / 8; ++w) {
        short8v o;
#pragma unroll
        for (int k = 0; k < 8; ++k)
            o[k] = (short)bfrn(fmaxf(acc[w * 8 + k] * inv, 0.f));
        *(short8v*)&orow[w * 8] = o;
    }
}

// ================= semantic softmax + combine (bf16 -> bf16), batched =================
struct CombBatch {
    const unsigned short* a[2];
    const unsigned short* b[2];
    unsigned short* o[2];
    int n8[2];
    int slot[2];
    float invN[2];
};

__global__ __launch_bounds__(256) void combine_b(CombBatch c, const float* __restrict__ sc) {
    const int ty = blockIdx.y;
    const int i = blockIdx.x * 256 + threadIdx.x;
    if (i >= c.n8[ty]) return;
    const float s0 = sc[c.slot[ty]] * c.invN[ty];
    const float s1 = sc[c.slot[ty] + 1] * c.invN[ty];
    const float m = fmaxf(s0, s1);
    const float e0 = expf(s0 - m), e1 = expf(s1 - m);
    const float w0 = e0 / (e0 + e1), w1 = e1 / (e0 + e1);
    const size_t o = (size_t)i * 8;
    ushort8v x = *(const ushort8v*)&c.a[ty][o];
    ushort8v y = *(const ushort8v*)&c.b[ty][o];
    short8v r;
#pragma unroll
    for (int k = 0; k < 8; ++k)
        r[k] = (short)bfrn(w0 * bf2f(x[k]) + w1 * bf2f(y[k]));
    *(short8v*)&c.o[ty][o] = r;
}

// final combine: bf16 pair -> f32 output
__global__ __launch_bounds__(256) void combine_out(
    const unsigned short* __restrict__ a, const unsigned short* __restrict__ b,
    float* __restrict__ out, const float* __restrict__ sc, int slot, float invN, int n8) {
    const int i = blockIdx.x * 256 + threadIdx.x;
    if (i >= n8) return;
    const float s0 = sc[slot] * invN, s1 = sc[slot + 1] * invN;
    const float m = fmaxf(s0, s1);
    const float e0 = expf(s0 - m), e1 = expf(s1 - m);
    const float w0 = e0 / (e0 + e1), w1 = e1 / (e0 + e1);
    const size_t o = (size_t)i * 8;
    ushort8v x = *(const ushort8v*)&a[o];
    ushort8v y = *(const ushort8v*)&b[o];
    float rr[8];
#pragma unroll
    for (int k = 0; k < 8; ++k) rr[k] = w0 * bf2f(x[k]) + w1 * bf2f(y[k]);
    float4 r0 = {rr[0], rr[1], rr[2], rr[3]};
    float4 r1 = {rr[4], rr[5], rr[6], rr[7]};
    *(float4*)&out[o] = r0;
    *(float4*)&out[o + 4] = r1;
}

extern "C" void kernel_launch(void* const* d_in, const int* in_sizes, int n_in,
                              void* d_out, int out_size, void* d_ws, size_t ws_size,
                              hipStream_t stream) {
    const float* x_a = (const float*)d_in[0];
    const float* x_p = (const float*)d_in[1];
    const int* src[4] = {(const int*)d_in[2], (const int*)d_in[4], (const int*)d_in[6], (const int*)d_in[8]};
    const int* dst[4] = {(const int*)d_in[3], (const int*)d_in[5], (const int*)d_in[7], (const int*)d_in[9]};
    const float* W1a = (const float*)d_in[10]; const float* b1a = (const float*)d_in[11];
    const float* W1p = (const float*)d_in[12]; const float* b1p = (const float*)d_in[13];
    const float* att1s = (const float*)d_in[14]; const float* att1d = (const float*)d_in[15];
    const float* q1 = (const float*)d_in[16];
    const float* k1W = (const float*)d_in[17]; const float* k1b = (const float*)d_in[18];
    const float* W2a = (const float*)d_in[19]; const float* b2a = (const float*)d_in[20];
    const float* W2p = (const float*)d_in[21]; const float* b2p = (const float*)d_in[22];
    const float* att2s = (const float*)d_in[23]; const float* att2d = (const float*)d_in[24];
    const float* q2 = (const float*)d_in[25];
    const float* k2W = (const float*)d_in[26]; const float* k2b = (const float*)d_in[27];

    const int NAp = NA + 128, NPp = NP + 128;
    char* wp = (char*)d_ws;
    unsigned short* xa_bf = (unsigned short*)wp; wp += (size_t)NAp * D1 * 2;
    unsigned short* xp_bf = (unsigned short*)wp; wp += (size_t)NPp * D1 * 2;
    unsigned short* h1a_bf = (unsigned short*)wp; wp += (size_t)NA * D1 * 2;
    unsigned short* h1p_bf = (unsigned short*)wp; wp += (size_t)NP * D1 * 2;
    unsigned short* a0 = (unsigned short*)wp; wp += (size_t)NPp * D1 * 2;
    unsigned short* a1 = (unsigned short*)wp; wp += (size_t)NAp * D1 * 2;
    unsigned short* a2 = (unsigned short*)wp; wp += (size_t)NPp * D1 * 2;
    unsigned short* a3 = (unsigned short*)wp; wp += (size_t)NAp * D1 * 2;
    float* sv = (float*)wp; wp += (size_t)(16 * NA + 16 * NP) * 4;
    float4* alogb = (float4*)wp; wp += (size_t)4 * NE * 16;
    float* sc = (float*)wp; wp += 16 * 4;
    int* rp_base = (int*)wp; wp += (size_t)(NP + NA + NP + NA + 4) * 4;
    int* cur_base = (int*)wp; wp += (size_t)(NP + NA + NP + NA) * 4;
    int* csrc_base = (int*)wp; wp += (size_t)4 * NE * 4;
    int* cdst_base = (int*)wp; wp += (size_t)4 * NE * 4;
    unsigned short* img_w1a = (unsigned short*)wp; wp += (size_t)8 * 2 * 256 * 32 * 2;
    unsigned short* img_w1p = (unsigned short*)wp; wp += (size_t)8 * 2 * 256 * 32 * 2;
    unsigned short* img_k1w = (unsigned short*)wp; wp += (size_t)8 * 2 * 256 * 32 * 2;
    unsigned short* img_w2a = (unsigned short*)wp; wp += (size_t)8 * 2 * 128 * 32 * 2;
    unsigned short* img_w2p = (unsigned short*)wp; wp += (size_t)8 * 2 * 128 * 32 * 2;
    unsigned short* img_k2w = (unsigned short*)wp; wp += (size_t)4 * 2 * 128 * 32 * 2;
    const size_t need_bytes = (size_t)(wp - (char*)d_ws);
    if (ws_size < need_bytes) return;

    int* rp[4] = {rp_base, rp_base + NP + 1, rp_base + NP + NA + 2, rp_base + NP + NA + NP + 3};
    int* cur[4] = {cur_base, cur_base + NP, cur_base + NP + NA, cur_base + NP + NA + NP};
    int* csrc[4]; int* cdst[4]; float4* alog[4];
    for (int i = 0; i < 4; ++i) {
        csrc[i] = csrc_base + (size_t)i * NE;
        cdst[i] = cdst_base + (size_t)i * NE;
        alog[i] = alogb + (size_t)i * NE;
    }
    float* ss0 = sv;             float* sd0 = ss0 + NA * 4;
    float* ss1 = sd0 + NP * 4;   float* sd1 = ss1 + NP * 4;
    float* ss2 = sd1 + NA * 4;   float* sd2 = ss2 + NP * 4;
    float* ss3 = sd2 + NP * 4;   float* sd3 = ss3 + NA * 4;
    unsigned short* res_p = a0;
    unsigned short* res_a = a1;
    unsigned short* h2a_bf = a2;
    unsigned short* h2p_bf = a2 + (size_t)NA * D2;
    unsigned short* g21 = a3;
    unsigned short* g23 = a3 + (size_t)NAp * D2;
    float* ss21 = sv;             float* sd21 = ss21 + NP * 4;
    float* ss23 = sd21 + NA * 4;  float* sd23 = ss23 + NA * 4;

    hipMemsetAsync(cur_base, 0, (size_t)(NP + NA + NP + NA) * sizeof(int), stream);
    hipMemsetAsync(sc, 0, 16 * sizeof(float), stream);
    PrepBatch pb = {{W1a, W1p, k1W, W2a, W2p, k2W},
                    {img_w1a, img_w1p, img_k1w, img_w2a, img_w2p, img_k2w},
                    {256, 256, 256, 128, 128, 128},
                    {8 * 2 * 256 * 4, 8 * 2 * 256 * 4, 8 * 2 * 256 * 4,
                     8 * 2 * 128 * 4, 8 * 2 * 128 * 4, 4 * 2 * 128 * 4}};
    w_prep<<<dim3(cdiv(8 * 2 * 256 * 4, 256), 6), 256, 0, stream>>>(pb);
    XrBatch xb = {{x_a, x_p}, {xa_bf, xp_bf}, {NA * D1 / 8, NP * D1 / 8}};
    xround_b<<<dim3(cdiv(NP * D1 / 8, 256), 2), 256, 0, stream>>>(xb);

    CsrBatch cb;
    for (int i = 0; i < 4; ++i) {
        cb.srcv[i] = src[i]; cb.dstv[i] = dst[i];
        cb.cnt[i] = cur[i]; cb.csrc[i] = csrc[i]; cb.cdst[i] = cdst[i];
    }
    count_deg_b<<<dim3(cdiv(NE, 256), 4), 256, 0, stream>>>(cb, NE);
    exscan4<<<4, 1024, 0, stream>>>(cur_base, rp_base);
    fill_csr_b<<<dim3(cdiv(NE, 256), 4), 256, 0, stream>>>(cb, NE);

    GemmBatch<2> t1 = {{xa_bf, xp_bf}, {img_w1a, img_w1p}, {b1a, b1p}, {h1a_bf, h1p_bf}, {NA, NP}};
    gemm_sw<256, false, 2><<<dim3(cdiv(NP, 64), 2), 256, 0, stream>>>(t1, nullptr, nullptr, 256);

    node_scoresN<64, 4><<<cdiv(NA * 4, 256), 256, 0, stream>>>(
        h1a_bf, att1s + 0 * 256, att1d + 1 * 256, att1s + 3 * 256, att1d + 3 * 256,
        ss0, sd1, ss3, sd3, NA);
    node_scoresN<64, 4><<<cdiv(NP * 4, 256), 256, 0, stream>>>(
        h1p_bf, att1d + 0 * 256, att1s + 1 * 256, att1s + 2 * 256, att1d + 2 * 256,
        sd0, ss1, ss2, sd2, NP);

    ElogBatch<4> el1 = {{csrc[0], csrc[1], csrc[2], csrc[3]},
                        {cdst[0], cdst[1], cdst[2], cdst[3]},
                        {ss0, ss1, ss2, ss3}, {sd0, sd1, sd2, sd3},
                        {alog[0], alog[1], alog[2], alog[3]}};
    edge_logits_b<4><<<dim3(cdiv(NE, 256), 4), 256, 0, stream>>>(el1, NE);
    AggBatch<4> ab1 = {{h1a_bf, h1p_bf, h1p_bf, h1a_bf},
                       {(const float*)alog[0], (const float*)alog[1], (const float*)alog[2], (const float*)alog[3]},
                       {csrc[0], csrc[1], csrc[2], csrc[3]},
                       {rp[0], rp[1], rp[2], rp[3]},
                       {a0, a1, a2, a3},
                       {NP, NA, NP, NA}};
    agg_b<256, 4><<<dim3(cdiv(NP, 16), 4), 256, 0, stream>>>(ab1);

    GemmBatch<4> s1 = {{a0, a2, a1, a3},
                       {img_k1w, img_k1w, img_k1w, img_k1w},
                       {k1b, k1b, k1b, k1b},
                       {nullptr, nullptr, nullptr, nullptr},
                       {NP, NP, NA, NA}};
    gemm_sw<256, true, 4><<<dim3(cdiv(NP, 64), 4), 256, 0, stream>>>(s1, q1, sc, 256);
    CombBatch c1 = {{a0, a1}, {a2, a3}, {res_p, res_a},
                    {NP * D1 / 8, NA * D1 / 8}, {0, 2}, {1.f / NP, 1.f / NA}};
    combine_b<<<dim3(cdiv(NP * D1 / 8, 256), 2), 256, 0, stream>>>(c1, sc);

    GemmBatch<2> t2 = {{res_a, res_p}, {img_w2a, img_w2p}, {b2a, b2p}, {h2a_bf, h2p_bf}, {NA, NP}};
    gemm_sw<128, false, 2><<<dim3(cdiv(NP, 128), 2), 256, 0, stream>>>(t2, nullptr, nullptr, 256);

    node_scoresN<32, 3><<<cdiv(NA * 4, 256), 256, 0, stream>>>(
        h2a_bf, att2d + 1 * 128, att2s + 3 * 128, att2d + 3 * 128, nullptr,
        sd21, ss23, sd23, nullptr, NA);
    node_scoresN<32, 1><<<cdiv(NP * 4, 256), 256, 0, stream>>>(
        h2p_bf, att2s + 1 * 128, nullptr, nullptr, nullptr,
        ss21, nullptr, nullptr, nullptr, NP);
    ElogBatch<2> el2 = {{csrc[1], csrc[3]}, {cdst[1], cdst[3]},
                        {ss21, ss23}, {sd21, sd23}, {alog[1], alog[3]}};
    edge_logits_b<2><<<dim3(cdiv(NE, 256), 2), 256, 0, stream>>>(el2, NE);
    AggBatch<2> ab2 = {{h2p_bf, h2a_bf},
                       {(const float*)alog[1], (const float*)alog[3]},
                       {csrc[1], csrc[3]}, {rp[1], rp[3]},
                       {g21, g23}, {NA, NA}};
    agg_b<128, 2><<<dim3(cdiv(NA, 16), 2), 256, 0, stream>>>(ab2);

    GemmBatch<2> s2 = {{g21, g23}, {img_k2w, img_k2w}, {k2b, k2b}, {nullptr, nullptr}, {NA, NA}};
    gemm_sw<128, true, 2><<<dim3(cdiv(NA, 128), 2), 256, 0, stream>>>(s2, q2, sc + 4, 128);
    combine_out<<<cdiv(NA * D2 / 8, 256), 256, 0, stream>>>(
        g21, g23, (float*)d_out, sc, 4, 1.f / NA, NA * D2 / 8);
}

// Round 8
// 416.990 us; speedup vs baseline: 1.3435x; 1.0221x over previous
//
#include <hip/hip_runtime.h>
#include <math.h>

// HAN (2-layer) on MI355X.
// GEMMs: A = plain bf16 image, W = split-bf16 hi/lo fragment-major image.
// Transform GEMMs use 2 MFMA products (hi+lo W); score GEMMs use 1 (hi only,
// error averages out in the mean-reduction). Both operands staged via
// global_load_lds (width 16) with k-slot XOR swizzle baked into the global
// source -> conflict-free ds_read_b128. 2-phase double-buffered K-loop
// (stage k+1 || compute k). Graph aggregation: bf16 gather, 16-lane group
// per dst node, batched. Layer-2 computes only author-needed work.

#define NA 20000
#define NP 30000
#define NE 200000
#define D1 256   // HID
#define D2 128   // OUT

typedef __attribute__((ext_vector_type(8))) short short8v;
typedef __attribute__((ext_vector_type(4))) float floatx4;
typedef __attribute__((ext_vector_type(8))) unsigned short ushort8v;
typedef __attribute__((ext_vector_type(4))) unsigned short ushort4v;

static __device__ __forceinline__ float lrelu(float x) { return x >= 0.f ? x : 0.2f * x; }

static __device__ __forceinline__ unsigned short bftrunc(float x) {
    return (unsigned short)(__float_as_uint(x) >> 16);
}
static __device__ __forceinline__ float bf2f(unsigned short b) {
    return __uint_as_float(((unsigned)b) << 16);
}
// round-to-nearest-even f32 -> bf16
static __device__ __forceinline__ unsigned short bfrn(float x) {
    unsigned u = __float_as_uint(x);
    return (unsigned short)((u + 0x7FFFu + ((u >> 16) & 1u)) >> 16);
}

typedef __attribute__((address_space(1))) const unsigned int as1_uint;
typedef __attribute__((address_space(3))) unsigned int as3_uint;
static __device__ __forceinline__ void gl_lds16(const void* g, void* l) {
    __builtin_amdgcn_global_load_lds((as1_uint*)g, (as3_uint*)l, 16, 0, 0);
}

static inline int cdiv(int a, int b) { return (a + b - 1) / b; }

// ================= CSR build (4 edge types batched) =================
struct CsrBatch {
    const int* srcv[4];
    const int* dstv[4];
    int* cnt[4];
    int* csrc[4];
    int* cdst[4];
};

__global__ __launch_bounds__(256) void count_deg_b(CsrBatch c, int n) {
    const int ty = blockIdx.y;
    const int i = blockIdx.x * 256 + threadIdx.x;
    if (i < n) atomicAdd(&c.cnt[ty][c.dstv[ty][i]], 1);
}

__global__ __launch_bounds__(256) void fill_csr_b(CsrBatch c, int n) {
    const int ty = blockIdx.y;
    const int i = blockIdx.x * 256 + threadIdx.x;
    if (i < n) {
        const int d = c.dstv[ty][i];
        const int p = atomicAdd(&c.cnt[ty][d], 1);
        c.csrc[ty][p] = c.srcv[ty][i];
        c.cdst[ty][p] = d;
    }
}

// 4 edge-type exclusive scans in one launch (blockIdx = type), wave-shuffle based.
__global__ __launch_bounds__(1024) void exscan4(int* __restrict__ curbase,
                                                int* __restrict__ rpbase) {
    const int off_c[4] = {0, NP, NP + NA, NP + NA + NP};
    const int off_r[4] = {0, NP + 1, NP + NA + 2, NP + NA + NP + 3};
    const int ns[4] = {NP, NA, NP, NA};
    const int b = blockIdx.x;
    int* cur = curbase + off_c[b];
    int* rp = rpbase + off_r[b];
    const int n = ns[b];
    __shared__ int wsum[16];
    __shared__ int carry_s;
    const int t = threadIdx.x, wv = t >> 6, ln = t & 63;
    if (t == 0) carry_s = 0;
    __syncthreads();
    for (int base = 0; base < n; base += 1024) {
        const int i = base + t;
        const int v = (i < n) ? cur[i] : 0;
        int x = v;
#pragma unroll
        for (int off = 1; off < 64; off <<= 1) {
            int y = __shfl_up(x, off);
            if (ln >= off) x += y;
        }
        if (ln == 63) wsum[wv] = x;
        __syncthreads();
        if (wv == 0) {
            int s = (ln < 16) ? wsum[ln] : 0;
#pragma unroll
            for (int off = 1; off < 16; off <<= 1) {
                int y = __shfl_up(s, off);
                if (ln >= off) s += y;
            }
            if (ln < 16) wsum[ln] = s;
        }
        __syncthreads();
        const int woff = (wv == 0) ? 0 : wsum[wv - 1];
        const int c = carry_s;
        const int ex = c + woff + x - v;
        if (i < n) { rp[i] = ex; cur[i] = ex; }
        __syncthreads();
        if (t == 1023) carry_s = c + wsum[15];
        __syncthreads();
    }
    if (t == 0) rp[n] = carry_s;
}

// ===== W -> split-bf16 fragment-major swizzled images: [kt][part][col][4 slots][8] =====
// Image position [col][slot] holds W k-elements of slot' = slot ^ ((col>>1)&3).
struct PrepBatch {
    const float* W[6];
    unsigned short* img[6];
    int N[6];
    int nsl[6];
};

__global__ __launch_bounds__(256) void w_prep(PrepBatch p) {
    const int m = blockIdx.y;
    const int idx = blockIdx.x * 256 + threadIdx.x;
    if (idx >= p.nsl[m]) return;
    const int N = p.N[m];
    const int slot = idx & 3;
    const int col = (idx >> 2) % N;
    const int rest = (idx >> 2) / N;
    const int part = rest & 1;
    const int kt = rest >> 1;
    const int ks = slot ^ ((col >> 1) & 3);
    unsigned short* dst = p.img[m] + (((size_t)(kt * 2 + part) * N + col) * 32) + slot * 8;
    const float* wsrc = p.W[m] + (size_t)(kt * 32 + ks * 8) * N + col;
    short8v o;
#pragma unroll
    for (int k = 0; k < 8; ++k) {
        const float x = wsrc[(size_t)k * N];
        const unsigned short hb = bftrunc(x);
        o[k] = part ? (short)bftrunc(x - bf2f(hb)) : (short)hb;
    }
    *(short8v*)dst = o;
}

// ============ x (f32) -> bf16-rn image (batched over 2) ============
struct XrBatch {
    const float* x[2];
    unsigned short* o[2];
    int n8[2];
};

__global__ __launch_bounds__(256) void xround_b(XrBatch p) {
    const int m = blockIdx.y;
    const int i = blockIdx.x * 256 + threadIdx.x;
    if (i >= p.n8[m]) return;
    const float* xp = p.x[m] + (size_t)i * 8;
    float4 v0 = *(const float4*)xp;
    float4 v1 = *(const float4*)(xp + 4);
    const float xs8[8] = {v0.x, v0.y, v0.z, v0.w, v1.x, v1.y, v1.z, v1.w};
    short8v o;
#pragma unroll
    for (int k = 0; k < 8; ++k) o[k] = (short)bfrn(xs8[k]);
    *(short8v*)&p.o[m][(size_t)i * 8] = o;
}

// ====== MFMA GEMM: A bf16 image, W split image; gl_lds staging; 2-phase dbuf ======
// SPLITW: use both W parts (2 MFMA) for full precision; else hi only (1 MFMA).
template <int NT>
struct GemmBatch {
    const unsigned short* A[NT];
    const unsigned short* Wimg[NT];
    const float* bias[NT];
    unsigned short* C[NT];
    int M[NT];
};

template <int BN, bool SCORE, bool SPLITW, int NT>
__global__ __launch_bounds__(256) void gemm_sw(
    GemmBatch<NT> g, const float* __restrict__ qv, float* __restrict__ score, int K) {
    constexpr int WGN = BN / 64;
    constexpr int WGM = 4 / WGN;
    constexpr int BM = WGM * 64;
    constexpr int NB = SPLITW ? 2 : 1;
    constexpr int ACH = BM * 32 * 2 / 1024;           // A 1KB chunks per k-tile
    constexpr int BCH = NB * BN * 32 * 2 / 1024;      // staged W chunks per k-tile
    constexpr int CPW = (ACH + BCH) / 4;              // chunks per wave
    constexpr int ASZ = BM * 64;                      // bytes per A buffer
    constexpr int BSZ = NB * BN * 64;                 // bytes per B buffer
    const int ty = blockIdx.y;
    const int M = g.M[ty];
    const int bm = blockIdx.x * BM;
    if (bm >= M) return;
    const unsigned short* __restrict__ A = g.A[ty];
    const unsigned short* __restrict__ Wi = g.Wimg[ty];
    const float* __restrict__ bias = g.bias[ty];
    __shared__ __attribute__((aligned(16))) unsigned short As[2][BM][32];
    __shared__ __attribute__((aligned(16))) unsigned short Bs[2][NB][BN][32];
    __shared__ float red[256];
    const int t = threadIdx.x;
    const int lane = t & 63, wid = t >> 6;
    const int wr = wid / WGN, wc = wid % WGN;
    const int fq = lane >> 4, fr = lane & 15;
    const int asl = (fq ^ ((fr >> 1) & 3)) * 16;      // swizzled read slot (A and B)
    const int lr = lane >> 2;                          // staging: row within 1KB chunk
    const int lks = (lane & 3) ^ ((lane >> 3) & 3);    // staging: swizzled source k-slot
    floatx4 acc[4][4];
#pragma unroll
    for (int i = 0; i < 4; ++i)
#pragma unroll
        for (int j = 0; j < 4; ++j) acc[i][j] = {0.f, 0.f, 0.f, 0.f};

    const int NK = K >> 5;
    // stage one k-tile into buffer b (image always holds 2 parts; read NB)
    auto STAGE = [&](int b, int ki) {
        const char* wbase = (const char*)Wi + (size_t)ki * (2 * BN * 64);
#pragma unroll
        for (int ci = 0; ci < CPW; ++ci) {
            const int c = wid * CPW + ci;
            if (c < ACH) {
                const int row = c * 16 + lr;
                const char* srcp = (const char*)(A + (size_t)(bm + row) * K + ki * 32 + lks * 8);
                gl_lds16(srcp, (char*)As + b * ASZ + c * 1024);
            } else {
                const int bc = c - ACH;
                gl_lds16(wbase + (size_t)bc * 1024 + lane * 16, (char*)Bs + b * BSZ + bc * 1024);
            }
        }
    };
    STAGE(0, 0);
    __syncthreads();
    int cur = 0;
    for (int ki = 0; ki < NK; ++ki) {
        if (ki + 1 < NK) STAGE(cur ^ 1, ki + 1);      // prefetch next tile (other buffer)
        short8v a[4], bh[4], bl[4];
#pragma unroll
        for (int f = 0; f < 4; ++f) {
            const int ar = wr * 64 + f * 16 + fr;
            a[f] = *(const short8v*)((const char*)As + cur * ASZ + ar * 64 + asl);
            const int bc = wc * 64 + f * 16 + fr;
            bh[f] = *(const short8v*)((const char*)Bs + cur * BSZ + bc * 64 + asl);
            if constexpr (SPLITW)
                bl[f] = *(const short8v*)((const char*)Bs + cur * BSZ + (size_t)BN * 64 + bc * 64 + asl);
        }
#pragma unroll
        for (int i = 0; i < 4; ++i)
#pragma unroll
            for (int j = 0; j < 4; ++j) {
                acc[i][j] = __builtin_amdgcn_mfma_f32_16x16x32_bf16(a[i], bh[j], acc[i][j], 0, 0, 0);
                if constexpr (SPLITW)
                    acc[i][j] = __builtin_amdgcn_mfma_f32_16x16x32_bf16(a[i], bl[j], acc[i][j], 0, 0, 0);
            }
        __syncthreads();   // drains prefetch (vmcnt) + protects cur^1 overwrite next iter
        cur ^= 1;
    }
    if constexpr (!SCORE) {
        unsigned short* __restrict__ Cb = g.C[ty];
#pragma unroll
        for (int i = 0; i < 4; ++i) {
            const int gr0 = bm + wr * 64 + i * 16 + fq * 4;
#pragma unroll
            for (int j = 0; j < 4; ++j) {
                const int col = wc * 64 + j * 16 + fr;
                const float b = bias[col];
#pragma unroll
                for (int r = 0; r < 4; ++r) {
                    const int gr = gr0 + r;
                    if (gr < M) Cb[(size_t)gr * BN + col] = bfrn(acc[i][j][r] + b);
                }
            }
        }
    } else {
        float partial = 0.f;
#pragma unroll
        for (int i = 0; i < 4; ++i) {
            const int gr0 = bm + wr * 64 + i * 16 + fq * 4;
#pragma unroll
            for (int j = 0; j < 4; ++j) {
                const int col = wc * 64 + j * 16 + fr;
                const float b = bias[col], q = qv[col];
#pragma unroll
                for (int r = 0; r < 4; ++r) {
                    if (gr0 + r < M) partial += tanhf(acc[i][j][r] + b) * q;
                }
            }
        }
        red[t] = partial;
        __syncthreads();
        for (int s = 128; s > 0; s >>= 1) {
            if (t < s) red[t] += red[t + s];
            __syncthreads();
        }
        if (t == 0) atomicAdd(&score[ty], red[0]);
    }
}

// ================ fused node attention-score dots (bf16 h, up to 4 att vectors) ================
template <int HD, int NSC>
__global__ __launch_bounds__(256) void node_scoresN(
    const unsigned short* __restrict__ hx,
    const float* __restrict__ a0, const float* __restrict__ a1,
    const float* __restrict__ a2, const float* __restrict__ a3,
    float* __restrict__ o0, float* __restrict__ o1,
    float* __restrict__ o2, float* __restrict__ o3, int n) {
    const int idx = blockIdx.x * blockDim.x + threadIdx.x;
    const int node = idx >> 2, hh = idx & 3;
    if (node >= n) return;
    const unsigned short* row = hx + (size_t)node * (4 * HD) + hh * HD;
    float s0 = 0.f, s1 = 0.f, s2 = 0.f, s3 = 0.f;
#pragma unroll
    for (int d = 0; d < HD; d += 4) {
        ushort4v xv = *(const ushort4v*)&row[d];
        const float x0 = bf2f(xv[0]), x1 = bf2f(xv[1]), x2 = bf2f(xv[2]), x3 = bf2f(xv[3]);
        float4 v = *(const float4*)&a0[hh * HD + d];
        s0 += x0 * v.x + x1 * v.y + x2 * v.z + x3 * v.w;
        if constexpr (NSC > 1) {
            v = *(const float4*)&a1[hh * HD + d];
            s1 += x0 * v.x + x1 * v.y + x2 * v.z + x3 * v.w;
        }
        if constexpr (NSC > 2) {
            v = *(const float4*)&a2[hh * HD + d];
            s2 += x0 * v.x + x1 * v.y + x2 * v.z + x3 * v.w;
        }
        if constexpr (NSC > 3) {
            v = *(const float4*)&a3[hh * HD + d];
            s3 += x0 * v.x + x1 * v.y + x2 * v.z + x3 * v.w;
        }
    }
    o0[idx] = s0;
    if constexpr (NSC > 1) o1[idx] = s1;
    if constexpr (NSC > 2) o2[idx] = s2;
    if constexpr (NSC > 3) o3[idx] = s3;
}

// ================= per-edge 4-head logits (batched) =================
template <int NT>
struct ElogBatch {
    const int* csrc[NT];
    const int* cdst[NT];
    const float* ss[NT];
    const float* sd[NT];
    float4* alog[NT];
};

template <int NT>
__global__ __launch_bounds__(256) void edge_logits_b(ElogBatch<NT> a, int n) {
    const int ty = blockIdx.y;
    const int i = blockIdx.x * 256 + threadIdx.x;
    if (i >= n) return;
    const int s = a.csrc[ty][i], d = a.cdst[ty][i];
    const float4 av = *(const float4*)&a.ss[ty][s * 4];
    const float4 bv = *(const float4*)&a.sd[ty][d * 4];
    float4 o = {lrelu(av.x + bv.x), lrelu(av.y + bv.y), lrelu(av.z + bv.z), lrelu(av.w + bv.w)};
    a.alog[ty][i] = o;
}

// ========== fused segment softmax + bf16 gather + relu -> bf16 out ==========
template <int EPL>
static __device__ __forceinline__ void accum(const unsigned short* p, float ea, float* acc) {
#pragma unroll
    for (int w = 0; w < EPL / 8; ++w) {
        ushort8v x = *(const ushort8v*)(p + w * 8);
#pragma unroll
        for (int k = 0; k < 8; ++k) acc[w * 8 + k] += bf2f(x[k]) * ea;
    }
}

template <int NT>
struct AggBatch {
    const unsigned short* xs[NT];
    const float* alog[NT];
    const int* csrc[NT];
    const int* rowptr[NT];
    unsigned short* out[NT];
    int ndst[NT];
};

template <int D, int NT>
__global__ __launch_bounds__(256) void agg_b(AggBatch<NT> a) {
    constexpr int EPL = D / 16;
    const int ty = blockIdx.y;
    const int gid = blockIdx.x * 16 + (threadIdx.x >> 4);
    if (gid >= a.ndst[ty]) return;
    const int g = threadIdx.x & 15;
    const int h = g >> 2, sub = g & 3;
    const int* __restrict__ rp = a.rowptr[ty];
    const int e0 = rp[gid], e1 = rp[gid + 1];
    const float* __restrict__ lg = a.alog[ty];
    const int* __restrict__ cs = a.csrc[ty];
    const unsigned short* __restrict__ xs = a.xs[ty];
    float mx = -INFINITY;
    for (int e = e0 + sub; e < e1; e += 4)
        mx = fmaxf(mx, lg[(size_t)e * 4 + h]);
    mx = fmaxf(mx, __shfl_xor(mx, 1));
    mx = fmaxf(mx, __shfl_xor(mx, 2));
    float acc[EPL] = {};
    float denom = 0.f;
    int e = e0;
    for (; e + 2 <= e1; e += 2) {
        const int r0 = cs[e], r1 = cs[e + 1];
        const float l0 = lg[(size_t)e * 4 + h];
        const float l1 = lg[(size_t)(e + 1) * 4 + h];
        const float ea0 = __expf(l0 - mx), ea1 = __expf(l1 - mx);
        denom += ea0 + ea1;
        accum<EPL>(xs + (size_t)r0 * D + g * EPL, ea0, acc);
        accum<EPL>(xs + (size_t)r1 * D + g * EPL, ea1, acc);
    }
    if (e < e1) {
        const int r0 = cs[e];
        const float l0 = lg[(size_t)e * 4 + h];
        const float ea0 = __expf(l0 - mx);
        denom += ea0;
        accum<EPL>(xs + (size_t)r0 * D + g * EPL, ea0, acc);
    }
    const float inv = 1.f / (denom + 1e-16f);
    unsigned short* __restrict__ orow = a.out[ty] + (size_t)gid * D + g * EPL;
#pragma unroll
    for (int w = 0; w < EPL / 8; ++w) {
        short8v o;
#pragma unroll
        for (int k = 0; k < 8; ++k)
            o[k] = (short)bfrn(fmaxf(acc[w * 8 + k] * inv, 0.f));
        *(short8v*)&orow[w * 8] = o;
    }
}

// ================= semantic softmax + combine (bf16 -> bf16), batched =================
struct CombBatch {
    const unsigned short* a[2];
    const unsigned short* b[2];
    unsigned short* o[2];
    int n8[2];
    int slot[2];
    float invN[2];
};

__global__ __launch_bounds__(256) void combine_b(CombBatch c, const float* __restrict__ sc) {
    const int ty = blockIdx.y;
    const int i = blockIdx.x * 256 + threadIdx.x;
    if (i >= c.n8[ty]) return;
    const float s0 = sc[c.slot[ty]] * c.invN[ty];
    const float s1 = sc[c.slot[ty] + 1] * c.invN[ty];
    const float m = fmaxf(s0, s1);
    const float e0 = expf(s0 - m), e1 = expf(s1 - m);
    const float w0 = e0 / (e0 + e1), w1 = e1 / (e0 + e1);
    const size_t o = (size_t)i * 8;
    ushort8v x = *(const ushort8v*)&c.a[ty][o];
    ushort8v y = *(const ushort8v*)&c.b[ty][o];
    short8v r;
#pragma unroll
    for (int k = 0; k < 8; ++k)
        r[k] = (short)bfrn(w0 * bf2f(x[k]) + w1 * bf2f(y[k]));
    *(short8v*)&c.o[ty][o] = r;
}

// final combine: bf16 pair -> f32 output
__global__ __launch_bounds__(256) void combine_out(
    const unsigned short* __restrict__ a, const unsigned short* __restrict__ b,
    float* __restrict__ out, const float* __restrict__ sc, int slot, float invN, int n8) {
    const int i = blockIdx.x * 256 + threadIdx.x;
    if (i >= n8) return;
    const float s0 = sc[slot] * invN, s1 = sc[slot + 1] * invN;
    const float m = fmaxf(s0, s1);
    const float e0 = expf(s0 - m), e1 = expf(s1 - m);
    const float w0 = e0 / (e0 + e1), w1 = e1 / (e0 + e1);
    const size_t o = (size_t)i * 8;
    ushort8v x = *(const ushort8v*)&a[o];
    ushort8v y = *(const ushort8v*)&b[o];
    float rr[8];
#pragma unroll
    for (int k = 0; k < 8; ++k) rr[k] = w0 * bf2f(x[k]) + w1 * bf2f(y[k]);
    float4 r0 = {rr[0], rr[1], rr[2], rr[3]};
    float4 r1 = {rr[4], rr[5], rr[6], rr[7]};
    *(float4*)&out[o] = r0;
    *(float4*)&out[o + 4] = r1;
}

extern "C" void kernel_launch(void* const* d_in, const int* in_sizes, int n_in,
                              void* d_out, int out_size, void* d_ws, size_t ws_size,
                              hipStream_t stream) {
    const float* x_a = (const float*)d_in[0];
    const float* x_p = (const float*)d_in[1];
    const int* src[4] = {(const int*)d_in[2], (const int*)d_in[4], (const int*)d_in[6], (const int*)d_in[8]};
    const int* dst[4] = {(const int*)d_in[3], (const int*)d_in[5], (const int*)d_in[7], (const int*)d_in[9]};
    const float* W1a = (const float*)d_in[10]; const float* b1a = (const float*)d_in[11];
    const float* W1p = (const float*)d_in[12]; const float* b1p = (const float*)d_in[13];
    const float* att1s = (const float*)d_in[14]; const float* att1d = (const float*)d_in[15];
    const float* q1 = (const float*)d_in[16];
    const float* k1W = (const float*)d_in[17]; const float* k1b = (const float*)d_in[18];
    const float* W2a = (const float*)d_in[19]; const float* b2a = (const float*)d_in[20];
    const float* W2p = (const float*)d_in[21]; const float* b2p = (const float*)d_in[22];
    const float* att2s = (const float*)d_in[23]; const float* att2d = (const float*)d_in[24];
    const float* q2 = (const float*)d_in[25];
    const float* k2W = (const float*)d_in[26]; const float* k2b = (const float*)d_in[27];

    const int NAp = NA + 128, NPp = NP + 128;
    char* wp = (char*)d_ws;
    unsigned short* xa_bf = (unsigned short*)wp; wp += (size_t)NAp * D1 * 2;
    unsigned short* xp_bf = (unsigned short*)wp; wp += (size_t)NPp * D1 * 2;
    unsigned short* h1a_bf = (unsigned short*)wp; wp += (size_t)NA * D1 * 2;
    unsigned short* h1p_bf = (unsigned short*)wp; wp += (size_t)NP * D1 * 2;
    unsigned short* a0 = (unsigned short*)wp; wp += (size_t)NPp * D1 * 2;
    unsigned short* a1 = (unsigned short*)wp; wp += (size_t)NAp * D1 * 2;
    unsigned short* a2 = (unsigned short*)wp; wp += (size_t)NPp * D1 * 2;
    unsigned short* a3 = (unsigned short*)wp; wp += (size_t)NAp * D1 * 2;
    float* sv = (float*)wp; wp += (size_t)(16 * NA + 16 * NP) * 4;
    float4* alogb = (float4*)wp; wp += (size_t)4 * NE * 16;
    float* sc = (float*)wp; wp += 16 * 4;
    int* rp_base = (int*)wp; wp += (size_t)(NP + NA + NP + NA + 4) * 4;
    int* cur_base = (int*)wp; wp += (size_t)(NP + NA + NP + NA) * 4;
    int* csrc_base = (int*)wp; wp += (size_t)4 * NE * 4;
    int* cdst_base = (int*)wp; wp += (size_t)4 * NE * 4;
    unsigned short* img_w1a = (unsigned short*)wp; wp += (size_t)8 * 2 * 256 * 32 * 2;
    unsigned short* img_w1p = (unsigned short*)wp; wp += (size_t)8 * 2 * 256 * 32 * 2;
    unsigned short* img_k1w = (unsigned short*)wp; wp += (size_t)8 * 2 * 256 * 32 * 2;
    unsigned short* img_w2a = (unsigned short*)wp; wp += (size_t)8 * 2 * 128 * 32 * 2;
    unsigned short* img_w2p = (unsigned short*)wp; wp += (size_t)8 * 2 * 128 * 32 * 2;
    unsigned short* img_k2w = (unsigned short*)wp; wp += (size_t)4 * 2 * 128 * 32 * 2;
    const size_t need_bytes = (size_t)(wp - (char*)d_ws);
    if (ws_size < need_bytes) return;

    int* rp[4] = {rp_base, rp_base + NP + 1, rp_base + NP + NA + 2, rp_base + NP + NA + NP + 3};
    int* cur[4] = {cur_base, cur_base + NP, cur_base + NP + NA, cur_base + NP + NA + NP};
    int* csrc[4]; int* cdst[4]; float4* alog[4];
    for (int i = 0; i < 4; ++i) {
        csrc[i] = csrc_base + (size_t)i * NE;
        cdst[i] = cdst_base + (size_t)i * NE;
        alog[i] = alogb + (size_t)i * NE;
    }
    float* ss0 = sv;             float* sd0 = ss0 + NA * 4;
    float* ss1 = sd0 + NP * 4;   float* sd1 = ss1 + NP * 4;
    float* ss2 = sd1 + NA * 4;   float* sd2 = ss2 + NP * 4;
    float* ss3 = sd2 + NP * 4;   float* sd3 = ss3 + NA * 4;
    unsigned short* res_p = a0;
    unsigned short* res_a = a1;
    unsigned short* h2a_bf = a2;
    unsigned short* h2p_bf = a2 + (size_t)NA * D2;
    unsigned short* g21 = a3;
    unsigned short* g23 = a3 + (size_t)NAp * D2;
    float* ss21 = sv;             float* sd21 = ss21 + NP * 4;
    float* ss23 = sd21 + NA * 4;  float* sd23 = ss23 + NA * 4;

    hipMemsetAsync(cur_base, 0, (size_t)(NP + NA + NP + NA) * sizeof(int), stream);
    hipMemsetAsync(sc, 0, 16 * sizeof(float), stream);
    PrepBatch pb = {{W1a, W1p, k1W, W2a, W2p, k2W},
                    {img_w1a, img_w1p, img_k1w, img_w2a, img_w2p, img_k2w},
                    {256, 256, 256, 128, 128, 128},
                    {8 * 2 * 256 * 4, 8 * 2 * 256 * 4, 8 * 2 * 256 * 4,
                     8 * 2 * 128 * 4, 8 * 2 * 128 * 4, 4 * 2 * 128 * 4}};
    w_prep<<<dim3(cdiv(8 * 2 * 256 * 4, 256), 6), 256, 0, stream>>>(pb);
    XrBatch xb = {{x_a, x_p}, {xa_bf, xp_bf}, {NA * D1 / 8, NP * D1 / 8}};
    xround_b<<<dim3(cdiv(NP * D1 / 8, 256), 2), 256, 0, stream>>>(xb);

    CsrBatch cb;
    for (int i = 0; i < 4; ++i) {
        cb.srcv[i] = src[i]; cb.dstv[i] = dst[i];
        cb.cnt[i] = cur[i]; cb.csrc[i] = csrc[i]; cb.cdst[i] = cdst[i];
    }
    count_deg_b<<<dim3(cdiv(NE, 256), 4), 256, 0, stream>>>(cb, NE);
    exscan4<<<4, 1024, 0, stream>>>(cur_base, rp_base);
    fill_csr_b<<<dim3(cdiv(NE, 256), 4), 256, 0, stream>>>(cb, NE);

    // layer-1 transforms (split W, 2-phase pipeline)
    GemmBatch<2> t1 = {{xa_bf, xp_bf}, {img_w1a, img_w1p}, {b1a, b1p}, {h1a_bf, h1p_bf}, {NA, NP}};
    gemm_sw<256, false, true, 2><<<dim3(cdiv(NP, 64), 2), 256, 0, stream>>>(t1, nullptr, nullptr, 256);

    node_scoresN<64, 4><<<cdiv(NA * 4, 256), 256, 0, stream>>>(
        h1a_bf, att1s + 0 * 256, att1d + 1 * 256, att1s + 3 * 256, att1d + 3 * 256,
        ss0, sd1, ss3, sd3, NA);
    node_scoresN<64, 4><<<cdiv(NP * 4, 256), 256, 0, stream>>>(
        h1p_bf, att1d + 0 * 256, att1s + 1 * 256, att1s + 2 * 256, att1d + 2 * 256,
        sd0, ss1, ss2, sd2, NP);

    ElogBatch<4> el1 = {{csrc[0], csrc[1], csrc[2], csrc[3]},
                        {cdst[0], cdst[1], cdst[2], cdst[3]},
                        {ss0, ss1, ss2, ss3}, {sd0, sd1, sd2, sd3},
                        {alog[0], alog[1], alog[2], alog[3]}};
    edge_logits_b<4><<<dim3(cdiv(NE, 256), 4), 256, 0, stream>>>(el1, NE);
    AggBatch<4> ab1 = {{h1a_bf, h1p_bf, h1p_bf, h1a_bf},
                       {(const float*)alog[0], (const float*)alog[1], (const float*)alog[2], (const float*)alog[3]},
                       {csrc[0], csrc[1], csrc[2], csrc[3]},
                       {rp[0], rp[1], rp[2], rp[3]},
                       {a0, a1, a2, a3},
                       {NP, NA, NP, NA}};
    agg_b<256, 4><<<dim3(cdiv(NP, 16), 4), 256, 0, stream>>>(ab1);

    // layer-1 semantic scores (hi-only W: error averages out in mean) + combine
    GemmBatch<4> s1 = {{a0, a2, a1, a3},
                       {img_k1w, img_k1w, img_k1w, img_k1w},
                       {k1b, k1b, k1b, k1b},
                       {nullptr, nullptr, nullptr, nullptr},
                       {NP, NP, NA, NA}};
    gemm_sw<256, true, false, 4><<<dim3(cdiv(NP, 64), 4), 256, 0, stream>>>(s1, q1, sc, 256);
    CombBatch c1 = {{a0, a1}, {a2, a3}, {res_p, res_a},
                    {NP * D1 / 8, NA * D1 / 8}, {0, 2}, {1.f / NP, 1.f / NA}};
    combine_b<<<dim3(cdiv(NP * D1 / 8, 256), 2), 256, 0, stream>>>(c1, sc);

    // layer-2 transforms (split W)
    GemmBatch<2> t2 = {{res_a, res_p}, {img_w2a, img_w2p}, {b2a, b2p}, {h2a_bf, h2p_bf}, {NA, NP}};
    gemm_sw<128, false, true, 2><<<dim3(cdiv(NP, 128), 2), 256, 0, stream>>>(t2, nullptr, nullptr, 256);

    node_scoresN<32, 3><<<cdiv(NA * 4, 256), 256, 0, stream>>>(
        h2a_bf, att2d + 1 * 128, att2s + 3 * 128, att2d + 3 * 128, nullptr,
        sd21, ss23, sd23, nullptr, NA);
    node_scoresN<32, 1><<<cdiv(NP * 4, 256), 256, 0, stream>>>(
        h2p_bf, att2s + 1 * 128, nullptr, nullptr, nullptr,
        ss21, nullptr, nullptr, nullptr, NP);
    ElogBatch<2> el2 = {{csrc[1], csrc[3]}, {cdst[1], cdst[3]},
                        {ss21, ss23}, {sd21, sd23}, {alog[1], alog[3]}};
    edge_logits_b<2><<<dim3(cdiv(NE, 256), 2), 256, 0, stream>>>(el2, NE);
    AggBatch<2> ab2 = {{h2p_bf, h2a_bf},
                       {(const float*)alog[1], (const float*)alog[3]},
                       {csrc[1], csrc[3]}, {rp[1], rp[3]},
                       {g21, g23}, {NA, NA}};
    agg_b<128, 2><<<dim3(cdiv(NA, 16), 2), 256, 0, stream>>>(ab2);

    // layer-2 semantic scores (hi-only W) -> output
    GemmBatch<2> s2 = {{g21, g23}, {img_k2w, img_k2w}, {k2b, k2b}, {nullptr, nullptr}, {NA, NA}};
    gemm_sw<128, true, false, 2><<<dim3(cdiv(NA, 128), 2), 256, 0, stream>>>(s2, q2, sc + 4, 128);
    combine_out<<<cdiv(NA * D2 / 8, 256), 256, 0, stream>>>(
        g21, g23, (float*)d_out, sc, 4, 1.f / NA, NA * D2 / 8);
}